// Round 1
// baseline (116.802 us; speedup 1.0000x reference)
//
#include <hip/hip_runtime.h>
#include <hip/hip_fp16.h>

#define MODV 26
#define HALFV 13
#define NV 64
#define BV 1024

// ---------------------------------------------------------------------------
// Kernel 1: per (l,i) row (4096 rows):
//   - softmax over 26 logits -> key_probs (output 1, fp32)
//   - for each p in [0,26): Kp[c] = sum_{k: p*k%26==c} kp[k]   (static unrolled)
//   - CRT (Z26 = Z2 x Z13) + sum/diff transform:
//       S'[r] = Kp[(14r)%26] + Kp[(13+14r)%26]
//       D'[r] = Kp[(14r)%26] - Kp[(13+14r)%26]
//   - pack fp16 into a 64B entry: halves [0..12]=S', [16..28]=D', rest 0
//   entry index = (l*26 + p)*64 + i   (64 B each) -> ws total 6,815,744 B
// ---------------------------------------------------------------------------
__global__ __launch_bounds__(64)
void prep_kernel(const float* __restrict__ key_param,
                 float* __restrict__ key_probs_out,
                 uint* __restrict__ ws)
{
    int row = blockIdx.x * 64 + threadIdx.x;   // row = l*64 + i
    float x[MODV];
    float m = -1e30f;
#pragma unroll
    for (int k = 0; k < MODV; k++) {
        x[k] = key_param[row * MODV + k];
        m = fmaxf(m, x[k]);
    }
    float s = 0.f;
#pragma unroll
    for (int k = 0; k < MODV; k++) { x[k] = expf(x[k] - m); s += x[k]; }
    float inv = 1.f / s;
#pragma unroll
    for (int k = 0; k < MODV; k++) {
        x[k] *= inv;
        key_probs_out[row * MODV + k] = x[k];
    }

    int l = row >> 6, i = row & 63;
#pragma unroll
    for (int p = 0; p < MODV; p++) {
        float Kp[MODV];
#pragma unroll
        for (int c = 0; c < MODV; c++) Kp[c] = 0.f;
#pragma unroll
        for (int k = 0; k < MODV; k++) Kp[(p * k) % MODV] += x[k];  // static idx

        uint hw[16];
#pragma unroll
        for (int j = 0; j < 16; j++) hw[j] = 0u;
#pragma unroll
        for (int r = 0; r < HALFV; r++) {
            int c0 = (14 * r) % MODV;        // even residue  (e=0)
            int c1 = (13 + 14 * r) % MODV;   // odd residue   (e=1)
            float Sv = Kp[c0] + Kp[c1];
            float Dv = Kp[c0] - Kp[c1];
            uint hs = (uint)__half_as_ushort(__float2half_rn(Sv));
            uint hd = (uint)__half_as_ushort(__float2half_rn(Dv));
            hw[(r >> 1)]     |= hs << (16 * (r & 1));
            hw[8 + (r >> 1)] |= hd << (16 * (r & 1));
        }
        uint4* dst = (uint4*)ws + (size_t)(((l * MODV + p) << 6) + i) * 4;
        dst[0] = make_uint4(hw[0],  hw[1],  hw[2],  hw[3]);
        dst[1] = make_uint4(hw[4],  hw[5],  hw[6],  hw[7]);
        dst[2] = make_uint4(hw[8],  hw[9],  hw[10], hw[11]);
        dst[3] = make_uint4(hw[12], hw[13], hw[14], hw[15]);
    }
}

__device__ __forceinline__ void cvt13(const uint4& a, const uint4& b, float* o)
{
    uint w[8] = {a.x, a.y, a.z, a.w, b.x, b.y, b.z, b.w};
#pragma unroll
    for (int j = 0; j < HALFV; j++) {
        uint word = w[j >> 1];
        ushort us = (ushort)((j & 1) ? (word >> 16) : (word & 0xffffu));
        o[j] = __half2float(__ushort_as_half(us));
    }
}

// ---------------------------------------------------------------------------
// Kernel 2: one lane per (b,i) chain. State (S[13],D[13]) in registers.
// Step l:  S <- S (conv13) S'_l ,  D <- D (conv13) D'_l    (exact, no scale)
// Init = transformed kernel at l=0 (since init dist IS prod[:,0]).
// Epilogue: u[(13e+14r)%26] = (S[r] +/- D[r]) * 0.5 / sum(S);  log(u+1e-12).
// ---------------------------------------------------------------------------
__global__ __launch_bounds__(256)
void chain_kernel(const int* __restrict__ P,
                  const uint4* __restrict__ ws,
                  float* __restrict__ out)
{
    int b = (blockIdx.x << 2) | (threadIdx.x >> 6);  // 4 waves/block, 1 b/wave
    int i = threadIdx.x & 63;
    const int* Pb = P + b * NV;

    float S[HALFV], D[HALFV];
    {
        int p0 = Pb[0];
        int idx = ((p0 << 6) + i) * 4;
        cvt13(ws[idx], ws[idx + 1], S);
        cvt13(ws[idx + 2], ws[idx + 3], D);
    }
    // software prefetch of step l=1
    uint4 c0, c1, c2, c3;
    {
        int p1 = Pb[1];
        int idx = (((MODV + p1) << 6) + i) * 4;
        c0 = ws[idx]; c1 = ws[idx + 1]; c2 = ws[idx + 2]; c3 = ws[idx + 3];
    }

    for (int l = 1; l < NV; l++) {
        int ln = (l + 1 < NV) ? (l + 1) : (NV - 1);   // tail: harmless re-load
        int pn = Pb[ln];
        int nidx = (((ln * MODV + pn) << 6) + i) * 4;
        uint4 n0 = ws[nidx], n1 = ws[nidx + 1], n2 = ws[nidx + 2], n3 = ws[nidx + 3];

        float Sp[HALFV], Dp[HALFV];
        cvt13(c0, c1, Sp);
        cvt13(c2, c3, Dp);

        float Sn[HALFV], Dn[HALFV];
#pragma unroll
        for (int r = 0; r < HALFV; r++) { Sn[r] = 0.f; Dn[r] = 0.f; }
#pragma unroll
        for (int m = 0; m < HALFV; m++) {
#pragma unroll
            for (int r = 0; r < HALFV; r++) {
                int t = m + r; if (t >= HALFV) t -= HALFV;   // compile-time
                Sn[t] = fmaf(S[m], Sp[r], Sn[t]);
                Dn[t] = fmaf(D[m], Dp[r], Dn[t]);
            }
        }
#pragma unroll
        for (int r = 0; r < HALFV; r++) { S[r] = Sn[r]; D[r] = Dn[r]; }
        c0 = n0; c1 = n1; c2 = n2; c3 = n3;
    }

    float tot = 0.f;
#pragma unroll
    for (int r = 0; r < HALFV; r++) tot += S[r];
    float invt = 0.5f / tot;

    float u[MODV];
#pragma unroll
    for (int r = 0; r < HALFV; r++) {
        u[(14 * r) % MODV]      = (S[r] + D[r]) * invt;
        u[(13 + 14 * r) % MODV] = (S[r] - D[r]) * invt;
    }
    float* o = out + (size_t)(b * NV + i) * MODV;
#pragma unroll
    for (int c = 0; c < MODV; c++) o[c] = logf(u[c] + 1e-12f);
}

extern "C" void kernel_launch(void* const* d_in, const int* in_sizes, int n_in,
                              void* d_out, int out_size, void* d_ws, size_t ws_size,
                              hipStream_t stream)
{
    const int*   P  = (const int*)d_in[0];      // (1024, 64) int32
    const float* kp = (const float*)d_in[1];    // (4096, 26) fp32
    float* out = (float*)d_out;                 // log_probs (1024*64*26) ++ key_probs (4096*26)
    float* key_probs_out = out + (size_t)BV * NV * MODV;
    uint* ws = (uint*)d_ws;                     // needs 6,815,744 B

    hipLaunchKernelGGL(prep_kernel, dim3(64), dim3(64), 0, stream,
                       kp, key_probs_out, ws);
    hipLaunchKernelGGL(chain_kernel, dim3(BV / 4), dim3(256), 0, stream,
                       P, (const uint4*)ws, out);
}

// Round 2
// 98.471 us; speedup vs baseline: 1.1862x; 1.1862x over previous
//
#include <hip/hip_runtime.h>
#include <hip/hip_fp16.h>

#define MODV 26
#define HALFV 13
#define NV 64
#define BV 1024

typedef float v2f __attribute__((ext_vector_type(2)));

// ---------------------------------------------------------------------------
// Table entry for (l,p,i): 64 B = 16 uints; uint r (r<13) packs half2
// (lo = S'[r], hi = D'[r]) where S'/D' are the CRT(Z2xZ13) sum/diff
// components of the scattered kernel Kp[c] = sum_{k: p*k%26==c} kp[l,i,k].
// entry index = (l*26 + p)*64 + i  -> ws total 64*26*64*64 = 6,815,744 B
// ---------------------------------------------------------------------------

// Kernel 1: one block per l (64 blocks x 256 threads). Threads split into 4
// groups of 64 lanes (i = tid&63, g = tid>>6); each group handles ~6-7
// compile-time-unrolled p values. Softmax recomputed per group (cheap).
__global__ __launch_bounds__(256)
void prep_kernel(const float* __restrict__ key_param,
                 float* __restrict__ key_probs_out,
                 uint* __restrict__ ws)
{
    int l = blockIdx.x;
    int t = threadIdx.x;
    int i = t & 63;
    int g = t >> 6;
    int row = (l << 6) + i;

    float x[MODV];
    float m = -1e30f;
#pragma unroll
    for (int k = 0; k < MODV; k++) {
        x[k] = key_param[row * MODV + k];
        m = fmaxf(m, x[k]);
    }
    float s = 0.f;
#pragma unroll
    for (int k = 0; k < MODV; k++) { x[k] = expf(x[k] - m); s += x[k]; }
    float inv = 1.f / s;
#pragma unroll
    for (int k = 0; k < MODV; k++) x[k] *= inv;

    if (g == 0) {
#pragma unroll
        for (int k = 0; k < MODV; k++) key_probs_out[row * MODV + k] = x[k];
    }

#pragma unroll
    for (int p = 0; p < MODV; p++) {
        if ((p * 4) / MODV != g) continue;   // static p, runtime wave-uniform g

        float Kp[MODV];
#pragma unroll
        for (int c = 0; c < MODV; c++) Kp[c] = 0.f;
#pragma unroll
        for (int k = 0; k < MODV; k++) Kp[(p * k) % MODV] += x[k];  // static idx

        uint hw[16];
#pragma unroll
        for (int j = 0; j < 16; j++) hw[j] = 0u;
#pragma unroll
        for (int r = 0; r < HALFV; r++) {
            int c0 = (14 * r) % MODV;        // even residue
            int c1 = (13 + 14 * r) % MODV;   // odd residue
            float Sv = Kp[c0] + Kp[c1];
            float Dv = Kp[c0] - Kp[c1];
            uint hs = (uint)__half_as_ushort(__float2half_rn(Sv));
            uint hd = (uint)__half_as_ushort(__float2half_rn(Dv));
            hw[r] = hs | (hd << 16);
        }
        uint4* dst = (uint4*)ws + ((size_t)(((l * MODV + p) << 6) + i)) * 4;
        dst[0] = make_uint4(hw[0],  hw[1],  hw[2],  hw[3]);
        dst[1] = make_uint4(hw[4],  hw[5],  hw[6],  hw[7]);
        dst[2] = make_uint4(hw[8],  hw[9],  hw[10], hw[11]);
        dst[3] = make_uint4(hw[12], hw[13], hw[14], hw[15]);
    }
}

__device__ __forceinline__ void unpack13(uint4 a, uint4 b, uint4 c, uint4 d,
                                         v2f* __restrict__ K)
{
    uint w[16] = {a.x,a.y,a.z,a.w, b.x,b.y,b.z,b.w,
                  c.x,c.y,c.z,c.w, d.x,d.y,d.z,d.w};
#pragma unroll
    for (int j = 0; j < HALFV; j++) {
        v2f v;
        v.x = __half2float(__ushort_as_half((ushort)(w[j] & 0xffffu)));
        v.y = __half2float(__ushort_as_half((ushort)(w[j] >> 16)));
        K[j] = v;
    }
}

// 13-point cyclic conv, (S,D) packed as float2 lanes -> v_pk_fma_f32
__device__ __forceinline__ void conv13(v2f* __restrict__ S,
                                       const v2f* __restrict__ K)
{
    v2f R[HALFV];
#pragma unroll
    for (int r = 0; r < HALFV; r++) { v2f z; z.x = 0.f; z.y = 0.f; R[r] = z; }
#pragma unroll
    for (int m = 0; m < HALFV; m++) {
#pragma unroll
        for (int r = 0; r < HALFV; r++) {
            int tt = m + r; if (tt >= HALFV) tt -= HALFV;   // compile-time
            R[tt] += S[m] * K[r];
        }
    }
#pragma unroll
    for (int r = 0; r < HALFV; r++) S[r] = R[r];
}

// ---------------------------------------------------------------------------
// Kernel 2: one block (4 waves) per b. Wave w conv-reduces segment
// l in [16w, 16w+16) (15 convs), then 2-level LDS tree combine (2 convs).
// Conv is commutative+associative and per-step renorm is a no-op (kernels
// sum to 1, values > 0), so association order is free.
// ---------------------------------------------------------------------------
__global__ __launch_bounds__(256, 4)
void chain_kernel(const int* __restrict__ P,
                  const uint4* __restrict__ ws,
                  float* __restrict__ out)
{
    __shared__ v2f sbuf[2][64][HALFV];   // 13,312 B

    int b = blockIdx.x;
    int w = threadIdx.x >> 6;
    int i = threadIdx.x & 63;
    const int* Pb = P + (b << 6);

    int base = w << 4;

    v2f SD[HALFV];
    {
        int idx = (((base * MODV + Pb[base]) << 6) + i) * 4;
        unpack13(ws[idx], ws[idx+1], ws[idx+2], ws[idx+3], SD);
    }
    // rolling prefetch of the next step's 64 B entry
    uint4 c0, c1, c2, c3;
    {
        int l = base + 1;
        int idx = (((l * MODV + Pb[l]) << 6) + i) * 4;
        c0 = ws[idx]; c1 = ws[idx+1]; c2 = ws[idx+2]; c3 = ws[idx+3];
    }

#pragma unroll 1
    for (int s = 1; s < 16; s++) {
        int ln = base + ((s + 1 < 16) ? (s + 1) : s);   // tail: harmless reload
        int nidx = (((ln * MODV + Pb[ln]) << 6) + i) * 4;
        uint4 n0 = ws[nidx], n1 = ws[nidx+1], n2 = ws[nidx+2], n3 = ws[nidx+3];

        v2f K[HALFV];
        unpack13(c0, c1, c2, c3, K);
        conv13(SD, K);

        c0 = n0; c1 = n1; c2 = n2; c3 = n3;
    }

    // tree combine: (w0 <- w1), (w2 <- w3) in parallel, then w0 <- w2
    if (w == 1) {
#pragma unroll
        for (int r = 0; r < HALFV; r++) sbuf[0][i][r] = SD[r];
    } else if (w == 3) {
#pragma unroll
        for (int r = 0; r < HALFV; r++) sbuf[1][i][r] = SD[r];
    }
    __syncthreads();
    if (w == 0) {
        v2f K[HALFV];
#pragma unroll
        for (int r = 0; r < HALFV; r++) K[r] = sbuf[0][i][r];
        conv13(SD, K);
    } else if (w == 2) {
        v2f K[HALFV];
#pragma unroll
        for (int r = 0; r < HALFV; r++) K[r] = sbuf[1][i][r];
        conv13(SD, K);
#pragma unroll
        for (int r = 0; r < HALFV; r++) sbuf[1][i][r] = SD[r];
    }
    __syncthreads();
    if (w == 0) {
        v2f K[HALFV];
#pragma unroll
        for (int r = 0; r < HALFV; r++) K[r] = sbuf[1][i][r];
        conv13(SD, K);

        float tot = 0.f;
#pragma unroll
        for (int r = 0; r < HALFV; r++) tot += SD[r].x;
        float invt = 0.5f / tot;

        float u[MODV];
#pragma unroll
        for (int r = 0; r < HALFV; r++) {
            u[(14 * r) % MODV]      = (SD[r].x + SD[r].y) * invt;
            u[(13 + 14 * r) % MODV] = (SD[r].x - SD[r].y) * invt;
        }
        float* o = out + ((size_t)(b << 6) + i) * MODV;
#pragma unroll
        for (int c = 0; c < MODV; c++) o[c] = logf(u[c] + 1e-12f);
    }
}

extern "C" void kernel_launch(void* const* d_in, const int* in_sizes, int n_in,
                              void* d_out, int out_size, void* d_ws, size_t ws_size,
                              hipStream_t stream)
{
    const int*   P  = (const int*)d_in[0];      // (1024, 64) int32
    const float* kp = (const float*)d_in[1];    // (4096, 26) fp32
    float* out = (float*)d_out;                 // log_probs ++ key_probs
    float* key_probs_out = out + (size_t)BV * NV * MODV;
    uint* ws = (uint*)d_ws;                     // 6,815,744 B used

    hipLaunchKernelGGL(prep_kernel, dim3(64), dim3(256), 0, stream,
                       kp, key_probs_out, ws);
    hipLaunchKernelGGL(chain_kernel, dim3(BV), dim3(256), 0, stream,
                       P, (const uint4*)ws, out);
}

// Round 3
// 98.437 us; speedup vs baseline: 1.1866x; 1.0003x over previous
//
#include <hip/hip_runtime.h>
#include <hip/hip_fp16.h>

#define MODV 26
#define HALFV 13
#define NV 64
#define BV 1024

typedef float v2f __attribute__((ext_vector_type(2)));

// Table entry for (l,p,i): 64 B = 16 uints; uint r (r<13) packs half2
// (lo = S'[r], hi = D'[r]), CRT(Z2xZ13) sum/diff components of the scattered
// kernel Kp[c] = sum_{k: p*k%26==c} kp[l,i,k]. Words 13..15 unused.
// entry uint-offset = ((l*26 + p)*64 + i)*16 ; ws usage 6,815,744 B.

__device__ __forceinline__ v2f cvtw(uint u)
{
    v2f v;
    v.x = __half2float(__ushort_as_half((ushort)(u & 0xffffu)));
    v.y = __half2float(__ushort_as_half((ushort)(u >> 16)));
    return v;
}

// ---------------------------------------------------------------------------
// Kernel 1: grid (64 l-slabs x 7 p-groups), 256 threads. Wave w handles
// p = 4*blockIdx.y + w (skip p>=26). Input slab staged coalesced via LDS.
// Each wave executes exactly ONE statically-unrolled p-block (wave-uniform
// branch), so all Kp[] scatter indices are compile-time.
// ---------------------------------------------------------------------------
__global__ __launch_bounds__(256)
void prep_kernel(const float* __restrict__ key_param,
                 float* __restrict__ key_probs_out,
                 uint* __restrict__ ws)
{
    __shared__ float slab[NV * MODV];   // 6656 B
    int l = blockIdx.x;
    int t = threadIdx.x;
    int i = t & 63;
    int w = t >> 6;
    int p = (blockIdx.y << 2) + w;

#pragma unroll
    for (int j = 0; j < 7; j++) {       // 7*256 = 1792 >= 1664
        int idx = t + j * 256;
        if (idx < NV * MODV) slab[idx] = key_param[l * NV * MODV + idx];
    }
    __syncthreads();

    float x[MODV];
    float m = -1e30f;
#pragma unroll
    for (int k = 0; k < MODV; k++) {
        x[k] = slab[i * MODV + k];      // stride 26 words: 2-way bank = free
        m = fmaxf(m, x[k]);
    }
    float s = 0.f;
#pragma unroll
    for (int k = 0; k < MODV; k++) { x[k] = __expf(x[k] - m); s += x[k]; }
    float inv = 1.f / s;
#pragma unroll
    for (int k = 0; k < MODV; k++) x[k] *= inv;

    if (blockIdx.y == 0 && w == 0) {
#pragma unroll
        for (int k = 0; k < MODV; k++)
            key_probs_out[((l << 6) + i) * MODV + k] = x[k];
    }
    if (p >= MODV) return;

#pragma unroll
    for (int pc = 0; pc < MODV; pc++) {
        if (pc != p) continue;          // wave-uniform; one block executes

        float Kp[MODV];
#pragma unroll
        for (int c = 0; c < MODV; c++) Kp[c] = 0.f;
#pragma unroll
        for (int k = 0; k < MODV; k++) Kp[(pc * k) % MODV] += x[k];  // static

        uint hw[HALFV];
#pragma unroll
        for (int r = 0; r < HALFV; r++) {
            int c0 = (14 * r) % MODV;
            int c1 = (13 + 14 * r) % MODV;
            float Sv = Kp[c0] + Kp[c1];
            float Dv = Kp[c0] - Kp[c1];
            uint hs = (uint)__half_as_ushort(__float2half_rn(Sv));
            uint hd = (uint)__half_as_ushort(__float2half_rn(Dv));
            hw[r] = hs | (hd << 16);
        }
        uint* dst = ws + ((size_t)(((l * MODV + pc) << 6) + i) << 4);
        *(uint4*)(dst)     = make_uint4(hw[0], hw[1], hw[2],  hw[3]);
        *(uint4*)(dst + 4) = make_uint4(hw[4], hw[5], hw[6],  hw[7]);
        *(uint4*)(dst + 8) = make_uint4(hw[8], hw[9], hw[10], hw[11]);
        dst[12] = hw[12];
    }
}

// 13-point cyclic conv against an already-unpacked kernel (used in combine)
__device__ __forceinline__ void conv13(v2f* __restrict__ S,
                                       const v2f* __restrict__ K)
{
    v2f R[HALFV];
#pragma unroll
    for (int m = 0; m < HALFV; m++) R[m] = S[m] * K[0];
#pragma unroll
    for (int r = 1; r < HALFV; r++) {
#pragma unroll
        for (int m = 0; m < HALFV; m++) {
            int tt = m + r; if (tt >= HALFV) tt -= HALFV;   // compile-time
            R[tt] += S[m] * K[r];
        }
    }
#pragma unroll
    for (int m = 0; m < HALFV; m++) S[m] = R[m];
}

// ---------------------------------------------------------------------------
// Kernel 2: one block (4 waves) per b. Wave w conv-reduces l in
// [16w,16w+16) (15 convs), LDS tree combine (2 levels), wave 0 epilogue.
// Kernel coefficients unpacked ON THE FLY (K = 2 regs transient) to keep
// live VGPRs ~90 (no spill at 4 waves/EU).
// ---------------------------------------------------------------------------
__global__ __launch_bounds__(256, 4)
void chain_kernel(const int* __restrict__ P,
                  const uint* __restrict__ ws,
                  float* __restrict__ out)
{
    __shared__ int Pl[NV];
    __shared__ v2f sbuf[2][64][HALFV];   // 13,312 B; stride 26 words: 2-way

    int b = blockIdx.x;
    int w = threadIdx.x >> 6;
    int i = threadIdx.x & 63;
    if (threadIdx.x < NV) Pl[threadIdx.x] = P[(b << 6) + threadIdx.x];
    __syncthreads();

    int base = w << 4;

    // init: SD = transformed kernel at l=base
    v2f SD[HALFV];
    {
        const uint* e = ws + ((size_t)(((base * MODV + Pl[base]) << 6) + i) << 4);
        uint4 a = *(const uint4*)e;
        uint4 bq = *(const uint4*)(e + 4);
        uint4 cq = *(const uint4*)(e + 8);
        uint w12 = e[12];
        uint wd[HALFV] = {a.x, a.y, a.z, a.w, bq.x, bq.y, bq.z, bq.w,
                          cq.x, cq.y, cq.z, cq.w, w12};
#pragma unroll
        for (int r = 0; r < HALFV; r++) SD[r] = cvtw(wd[r]);
    }

    // rolling prefetch: words 0..12 of next step's entry
    uint4 n0, n1, n2; uint n12;
    {
        int l = base + 1;
        const uint* e = ws + ((size_t)(((l * MODV + Pl[l]) << 6) + i) << 4);
        n0 = *(const uint4*)e; n1 = *(const uint4*)(e + 4);
        n2 = *(const uint4*)(e + 8); n12 = e[12];
    }

#pragma unroll 1
    for (int s = 1; s < 16; s++) {
        uint cw[HALFV] = {n0.x, n0.y, n0.z, n0.w, n1.x, n1.y, n1.z, n1.w,
                          n2.x, n2.y, n2.z, n2.w, n12};
        if (s < 15) {
            int l = base + s + 1;
            const uint* e = ws + ((size_t)(((l * MODV + Pl[l]) << 6) + i) << 4);
            n0 = *(const uint4*)e; n1 = *(const uint4*)(e + 4);
            n2 = *(const uint4*)(e + 8); n12 = e[12];
        }

        v2f R[HALFV];
        {
            v2f K = cvtw(cw[0]);
#pragma unroll
            for (int m = 0; m < HALFV; m++) R[m] = SD[m] * K;
        }
#pragma unroll
        for (int r = 1; r < HALFV; r++) {
            v2f K = cvtw(cw[r]);
#pragma unroll
            for (int m = 0; m < HALFV; m++) {
                int tt = m + r; if (tt >= HALFV) tt -= HALFV;
                R[tt] += SD[m] * K;
            }
        }
#pragma unroll
        for (int m = 0; m < HALFV; m++) SD[m] = R[m];
    }

    // tree combine: (w0 <- w1), (w2 <- w3), then w0 <- w2
    if (w == 1) {
#pragma unroll
        for (int r = 0; r < HALFV; r++) sbuf[0][i][r] = SD[r];
    } else if (w == 3) {
#pragma unroll
        for (int r = 0; r < HALFV; r++) sbuf[1][i][r] = SD[r];
    }
    __syncthreads();
    if (w == 0) {
        v2f K[HALFV];
#pragma unroll
        for (int r = 0; r < HALFV; r++) K[r] = sbuf[0][i][r];
        conv13(SD, K);
    } else if (w == 2) {
        v2f K[HALFV];
#pragma unroll
        for (int r = 0; r < HALFV; r++) K[r] = sbuf[1][i][r];
        conv13(SD, K);
#pragma unroll
        for (int r = 0; r < HALFV; r++) sbuf[1][i][r] = SD[r];
    }
    __syncthreads();
    if (w == 0) {
        v2f K[HALFV];
#pragma unroll
        for (int r = 0; r < HALFV; r++) K[r] = sbuf[1][i][r];
        conv13(SD, K);

        float tot = 0.f;
#pragma unroll
        for (int r = 0; r < HALFV; r++) tot += SD[r].x;
        float invt = 0.5f / tot;

        float u[MODV];
#pragma unroll
        for (int r = 0; r < HALFV; r++) {
            u[(14 * r) % MODV]      = (SD[r].x + SD[r].y) * invt;
            u[(13 + 14 * r) % MODV] = (SD[r].x - SD[r].y) * invt;
        }
        float* o = out + ((size_t)(b << 6) + i) * MODV;
#pragma unroll
        for (int c = 0; c < MODV; c++) o[c] = __logf(u[c] + 1e-12f);
    }
}

extern "C" void kernel_launch(void* const* d_in, const int* in_sizes, int n_in,
                              void* d_out, int out_size, void* d_ws, size_t ws_size,
                              hipStream_t stream)
{
    const int*   P  = (const int*)d_in[0];      // (1024, 64) int32
    const float* kp = (const float*)d_in[1];    // (4096, 26) fp32
    float* out = (float*)d_out;                 // log_probs ++ key_probs
    float* key_probs_out = out + (size_t)BV * NV * MODV;
    uint* ws = (uint*)d_ws;                     // 6,815,744 B used

    hipLaunchKernelGGL(prep_kernel, dim3(64, 7), dim3(256), 0, stream,
                       kp, key_probs_out, ws);
    hipLaunchKernelGGL(chain_kernel, dim3(BV), dim3(256), 0, stream,
                       P, ws, out);
}

// Round 4
// 89.025 us; speedup vs baseline: 1.3120x; 1.1057x over previous
//
#include <hip/hip_runtime.h>
#include <hip/hip_fp16.h>

#define MODV 26
#define HALFV 13
#define NV 64
#define BV 1024

typedef float v2f __attribute__((ext_vector_type(2)));

// ---------------------------------------------------------------------------
// Spectral representation. For each (l,p,i) the scattered kernel
// Kp[c] = sum_{k: p*k%26==c} softmax(key_param[l,i,:])[k] is CRT-split
// (Z26 = Z2 x Z13) into S[r] = Kp[even]+Kp[odd], D[r] = Kp[even]-Kp[odd],
// then 13-point DFT'd:  X_j = sum_r x[r] e^{-2pi i jr/13}, j = 0..6
// (conjugate symmetry gives the rest; X_0 real). Circular conv over Z13
// == pointwise complex product of spectra, so the 63-step chain becomes
// 63 pointwise products + ONE inverse DFT at the end.
// Entry = 13 half2 words: w[0..6] = (S_re_j, D_re_j), w[7..12] = (S_im_j,
// D_im_j) for j=1..6. uint-offset = ((l*26+p)*64 + i)*16 (64 B stride).
// ws usage 6,815,744 B.
// ---------------------------------------------------------------------------

__device__ __forceinline__ v2f cvtw(uint u)
{
    v2f v;
    v.x = __half2float(__ushort_as_half((ushort)(u & 0xffffu)));
    v.y = __half2float(__ushort_as_half((ushort)(u >> 16)));
    return v;
}

__device__ __forceinline__ uint packw(v2f v)
{
    uint hs = (uint)__half_as_ushort(__float2half_rn(v.x));
    uint hd = (uint)__half_as_ushort(__float2half_rn(v.y));
    return hs | (hd << 16);
}

// pointwise spectral product: state (RE[0..6], IM[1..6]) *= K (same layout,
// K[0..6]=re, K[7..12]=im(j=1..6))
__device__ __forceinline__ void mulspec(v2f* __restrict__ RE,
                                        v2f* __restrict__ IM,
                                        const v2f* __restrict__ K)
{
    RE[0] *= K[0];
#pragma unroll
    for (int j = 1; j < 7; j++) {
        v2f kr = K[j], ki = K[6 + j];
        v2f nre = RE[j] * kr - IM[j] * ki;
        v2f nim = RE[j] * ki + IM[j] * kr;
        RE[j] = nre; IM[j] = nim;
    }
}

// ---------------------------------------------------------------------------
// Kernel 1: grid (64 l-slabs x 7 p-groups) x 256. Wave w handles
// p = 4*blockIdx.y + w (skip p>=26); one statically-unrolled p-block per
// wave (wave-uniform branch -> compile-time scatter indices).
// ---------------------------------------------------------------------------
__global__ __launch_bounds__(256)
void prep_kernel(const float* __restrict__ key_param,
                 float* __restrict__ key_probs_out,
                 uint* __restrict__ ws)
{
    __shared__ float slab[NV * MODV];   // 6656 B
    int l = blockIdx.x;
    int t = threadIdx.x;
    int i = t & 63;
    int w = t >> 6;
    int p = (blockIdx.y << 2) + w;

#pragma unroll
    for (int j = 0; j < 7; j++) {
        int idx = t + j * 256;
        if (idx < NV * MODV) slab[idx] = key_param[l * NV * MODV + idx];
    }
    __syncthreads();

    float x[MODV];
    float m = -1e30f;
#pragma unroll
    for (int k = 0; k < MODV; k++) {
        x[k] = slab[i * MODV + k];
        m = fmaxf(m, x[k]);
    }
    float s = 0.f;
#pragma unroll
    for (int k = 0; k < MODV; k++) { x[k] = __expf(x[k] - m); s += x[k]; }
    float inv = 1.f / s;
#pragma unroll
    for (int k = 0; k < MODV; k++) x[k] *= inv;

    if (blockIdx.y == 0 && w == 0) {
#pragma unroll
        for (int k = 0; k < MODV; k++)
            key_probs_out[((l << 6) + i) * MODV + k] = x[k];
    }
    if (p >= MODV) return;

    // twiddles cos/sin(2*pi*k/13), k=0..12
    float c13[HALFV], s13[HALFV];
#pragma unroll
    for (int k = 0; k < HALFV; k++) {
        float a = 0.4833219467f * (float)k;    // 2*pi/13
        __sincosf(a, &s13[k], &c13[k]);
    }

#pragma unroll
    for (int pc = 0; pc < MODV; pc++) {
        if (pc != p) continue;          // wave-uniform; one block executes

        float Kp[MODV];
#pragma unroll
        for (int c = 0; c < MODV; c++) Kp[c] = 0.f;
#pragma unroll
        for (int k = 0; k < MODV; k++) Kp[(pc * k) % MODV] += x[k];  // static

        v2f V[HALFV];                    // (S[r], D[r])
#pragma unroll
        for (int r = 0; r < HALFV; r++) {
            int c0 = (14 * r) % MODV;
            int c1 = (13 + 14 * r) % MODV;
            v2f v; v.x = Kp[c0] + Kp[c1]; v.y = Kp[c0] - Kp[c1];
            V[r] = v;
        }

        uint hw[HALFV];
        {   // j = 0 (DC, real)
            v2f acc = V[0];
#pragma unroll
            for (int r = 1; r < HALFV; r++) acc += V[r];
            hw[0] = packw(acc);
        }
#pragma unroll
        for (int j = 1; j < 7; j++) {
            v2f re = V[0];
            v2f im; im.x = 0.f; im.y = 0.f;
#pragma unroll
            for (int r = 1; r < HALFV; r++) {
                int a = (j * r) % HALFV;            // compile-time
                re += V[r] * c13[a];
                im -= V[r] * s13[a];
            }
            hw[j]     = packw(re);
            hw[6 + j] = packw(im);
        }
        uint* dst = ws + ((size_t)(((l * MODV + pc) << 6) + i) << 4);
        *(uint4*)(dst)     = make_uint4(hw[0], hw[1], hw[2],  hw[3]);
        *(uint4*)(dst + 4) = make_uint4(hw[4], hw[5], hw[6],  hw[7]);
        *(uint4*)(dst + 8) = make_uint4(hw[8], hw[9], hw[10], hw[11]);
        dst[12] = hw[12];
    }
}

// ---------------------------------------------------------------------------
// Kernel 2: one block (4 waves) per b. Wave w pointwise-multiplies the 16
// spectra for l in [16w,16w+16), LDS tree combine (2 levels, also pointwise),
// wave 0 does the single inverse DFT + unscramble + log epilogue.
// ---------------------------------------------------------------------------
__global__ __launch_bounds__(256, 4)
void chain_kernel(const int* __restrict__ P,
                  const uint* __restrict__ ws,
                  float* __restrict__ out)
{
    __shared__ int Pl[NV];
    __shared__ v2f sbuf[2][64][HALFV];   // 13,312 B

    int b = blockIdx.x;
    int w = threadIdx.x >> 6;
    int i = threadIdx.x & 63;
    if (threadIdx.x < NV) Pl[threadIdx.x] = P[(b << 6) + threadIdx.x];
    __syncthreads();

    int base = w << 4;

    v2f RE[7], IM[7];                    // IM[0] unused
    {
        const uint* e = ws + ((size_t)(((base * MODV + Pl[base]) << 6) + i) << 4);
        uint4 a = *(const uint4*)e;
        uint4 bq = *(const uint4*)(e + 4);
        uint4 cq = *(const uint4*)(e + 8);
        uint w12 = e[12];
        uint wd[HALFV] = {a.x, a.y, a.z, a.w, bq.x, bq.y, bq.z, bq.w,
                          cq.x, cq.y, cq.z, cq.w, w12};
#pragma unroll
        for (int j = 0; j < 7; j++) RE[j] = cvtw(wd[j]);
#pragma unroll
        for (int j = 1; j < 7; j++) IM[j] = cvtw(wd[6 + j]);
    }

    uint4 n0, n1, n2; uint n12;
    {
        int l = base + 1;
        const uint* e = ws + ((size_t)(((l * MODV + Pl[l]) << 6) + i) << 4);
        n0 = *(const uint4*)e; n1 = *(const uint4*)(e + 4);
        n2 = *(const uint4*)(e + 8); n12 = e[12];
    }

#pragma unroll 1
    for (int s = 1; s < 16; s++) {
        uint cw[HALFV] = {n0.x, n0.y, n0.z, n0.w, n1.x, n1.y, n1.z, n1.w,
                          n2.x, n2.y, n2.z, n2.w, n12};
        if (s < 15) {
            int l = base + s + 1;
            const uint* e = ws + ((size_t)(((l * MODV + Pl[l]) << 6) + i) << 4);
            n0 = *(const uint4*)e; n1 = *(const uint4*)(e + 4);
            n2 = *(const uint4*)(e + 8); n12 = e[12];
        }

        RE[0] *= cvtw(cw[0]);
#pragma unroll
        for (int j = 1; j < 7; j++) {
            v2f kr = cvtw(cw[j]), ki = cvtw(cw[6 + j]);
            v2f nre = RE[j] * kr - IM[j] * ki;
            v2f nim = RE[j] * ki + IM[j] * kr;
            RE[j] = nre; IM[j] = nim;
        }
    }

    // tree combine: (w0 <- w1), (w2 <- w3), then w0 <- w2 (pointwise products)
    if (w == 1 || w == 3) {
        int buf = w >> 1;
#pragma unroll
        for (int j = 0; j < 7; j++) sbuf[buf][i][j] = RE[j];
#pragma unroll
        for (int j = 1; j < 7; j++) sbuf[buf][i][6 + j] = IM[j];
    }
    __syncthreads();
    if (w == 0) {
        v2f K[HALFV];
#pragma unroll
        for (int r = 0; r < HALFV; r++) K[r] = sbuf[0][i][r];
        mulspec(RE, IM, K);
    } else if (w == 2) {
        v2f K[HALFV];
#pragma unroll
        for (int r = 0; r < HALFV; r++) K[r] = sbuf[1][i][r];
        mulspec(RE, IM, K);
#pragma unroll
        for (int j = 0; j < 7; j++) sbuf[1][i][j] = RE[j];
#pragma unroll
        for (int j = 1; j < 7; j++) sbuf[1][i][6 + j] = IM[j];
    }
    __syncthreads();
    if (w == 0) {
        v2f K[HALFV];
#pragma unroll
        for (int r = 0; r < HALFV; r++) K[r] = sbuf[1][i][r];
        mulspec(RE, IM, K);

        // inverse DFT (unnormalized; uniform scale cancels in normalization):
        // V[r] = RE[0] + 2*sum_j ( RE[j]*cos(2pi jr/13) - IM[j]*sin(...) )
        float c13[HALFV], s13[HALFV];
#pragma unroll
        for (int k = 0; k < HALFV; k++) {
            float a = 0.4833219467f * (float)k;
            __sincosf(a, &s13[k], &c13[k]);
        }
        v2f V[HALFV];
#pragma unroll
        for (int r = 0; r < HALFV; r++) {
            v2f acc = RE[0];
#pragma unroll
            for (int j = 1; j < 7; j++) {
                int a = (j * r) % HALFV;            // compile-time
                acc += (RE[j] * c13[a] - IM[j] * s13[a]) * 2.0f;
            }
            V[r] = acc;
        }

        float tot = 0.f;
#pragma unroll
        for (int r = 0; r < HALFV; r++) tot += V[r].x;
        float invt = 0.5f / tot;

        float u[MODV];
#pragma unroll
        for (int r = 0; r < HALFV; r++) {
            u[(14 * r) % MODV]      = (V[r].x + V[r].y) * invt;
            u[(13 + 14 * r) % MODV] = (V[r].x - V[r].y) * invt;
        }
        float* o = out + ((size_t)(b << 6) + i) * MODV;
#pragma unroll
        for (int c = 0; c < MODV; c++) o[c] = __logf(u[c] + 1e-12f);
    }
}

extern "C" void kernel_launch(void* const* d_in, const int* in_sizes, int n_in,
                              void* d_out, int out_size, void* d_ws, size_t ws_size,
                              hipStream_t stream)
{
    const int*   P  = (const int*)d_in[0];      // (1024, 64) int32
    const float* kp = (const float*)d_in[1];    // (4096, 26) fp32
    float* out = (float*)d_out;                 // log_probs ++ key_probs
    float* key_probs_out = out + (size_t)BV * NV * MODV;
    uint* ws = (uint*)d_ws;                     // 6,815,744 B used

    hipLaunchKernelGGL(prep_kernel, dim3(64, 7), dim3(256), 0, stream,
                       kp, key_probs_out, ws);
    hipLaunchKernelGGL(chain_kernel, dim3(BV), dim3(256), 0, stream,
                       P, ws, out);
}

// Round 5
// 88.245 us; speedup vs baseline: 1.3236x; 1.0088x over previous
//
#include <hip/hip_runtime.h>
#include <hip/hip_fp16.h>

#define MODV 26
#define HALFV 13
#define NV 64
#define BV 1024

typedef float v2f __attribute__((ext_vector_type(2)));
typedef _Float16 h2 __attribute__((ext_vector_type(2)));

// ---------------------------------------------------------------------------
// Spectral representation (unchanged from R4). For each (l,p,i):
//   Kp[c] = sum_{k: p*k%26==c} softmax(key_param[l,i,:])[k]
// CRT split (Z26 = Z2 x Z13): S[r] = Kp[even]+Kp[odd], D[r] = Kp[even]-Kp[odd]
// 13-pt DFT: X_j = sum_r x[r] e^{-2pi i jr/13}, j=0..6 (X_0 real).
// Chain = 63 pointwise complex products + ONE inverse DFT at the end.
// Entry = 13 half2 words: w[0..6]=(S_re,D_re) j=0..6, w[7..12]=(S_im,D_im)
// j=1..6. uint-offset = ((l*26+p)*64+i)*16 (64 B stride). ws use 6.8 MB.
//
// R5: chain arithmetic in PACKED FP16 (v_pk_fma_f16) directly on the loaded
// words — no f16->f32 unpack in the hot loop. Safe because the pipeline is
// purely multiplicative until the epilogue: non-DC coefficients underflow to
// 0 (same as ref fp32), DC rounding cancels exactly in the normalization.
// ---------------------------------------------------------------------------

__device__ __forceinline__ h2 bch2(uint u) { return __builtin_bit_cast(h2, u); }
__device__ __forceinline__ uint bcu(h2 v) { return __builtin_bit_cast(uint, v); }

__device__ __forceinline__ uint packw(v2f v)
{
    uint hs = (uint)__half_as_ushort(__float2half_rn(v.x));
    uint hd = (uint)__half_as_ushort(__float2half_rn(v.y));
    return hs | (hd << 16);
}

// state (RE[0..6], IM[1..6]) *= spectrum in packed words w13[0..12]
__device__ __forceinline__ void mulspec_w(h2* __restrict__ RE,
                                          h2* __restrict__ IM,
                                          const uint* __restrict__ w13)
{
    RE[0] *= bch2(w13[0]);
#pragma unroll
    for (int j = 1; j < 7; j++) {
        h2 kr = bch2(w13[j]), ki = bch2(w13[6 + j]);
        h2 nre = RE[j] * kr - IM[j] * ki;
        h2 nim = RE[j] * ki + IM[j] * kr;
        RE[j] = nre; IM[j] = nim;
    }
}

// ---------------------------------------------------------------------------
// Kernel 1: grid (64 l-slabs x 7 p-groups) x 256. Wave w handles
// p = 4*blockIdx.y + w (skip p>=26); one statically-unrolled p-block per
// wave (wave-uniform branch -> compile-time scatter indices).
// ---------------------------------------------------------------------------
__global__ __launch_bounds__(256)
void prep_kernel(const float* __restrict__ key_param,
                 float* __restrict__ key_probs_out,
                 uint* __restrict__ ws)
{
    __shared__ float slab[NV * MODV];   // 6656 B
    int l = blockIdx.x;
    int t = threadIdx.x;
    int i = t & 63;
    int w = t >> 6;
    int p = (blockIdx.y << 2) + w;

#pragma unroll
    for (int j = 0; j < 7; j++) {
        int idx = t + j * 256;
        if (idx < NV * MODV) slab[idx] = key_param[l * NV * MODV + idx];
    }
    __syncthreads();

    float x[MODV];
    float m = -1e30f;
#pragma unroll
    for (int k = 0; k < MODV; k++) {
        x[k] = slab[i * MODV + k];
        m = fmaxf(m, x[k]);
    }
    float s = 0.f;
#pragma unroll
    for (int k = 0; k < MODV; k++) { x[k] = __expf(x[k] - m); s += x[k]; }
    float inv = 1.f / s;
#pragma unroll
    for (int k = 0; k < MODV; k++) x[k] *= inv;

    if (blockIdx.y == 0 && w == 0) {
#pragma unroll
        for (int k = 0; k < MODV; k++)
            key_probs_out[((l << 6) + i) * MODV + k] = x[k];
    }
    if (p >= MODV) return;

    float c13[HALFV], s13[HALFV];
#pragma unroll
    for (int k = 0; k < HALFV; k++) {
        float a = 0.4833219467f * (float)k;    // 2*pi/13
        __sincosf(a, &s13[k], &c13[k]);
    }

#pragma unroll
    for (int pc = 0; pc < MODV; pc++) {
        if (pc != p) continue;          // wave-uniform; one block executes

        float Kp[MODV];
#pragma unroll
        for (int c = 0; c < MODV; c++) Kp[c] = 0.f;
#pragma unroll
        for (int k = 0; k < MODV; k++) Kp[(pc * k) % MODV] += x[k];  // static

        v2f V[HALFV];                    // (S[r], D[r])
#pragma unroll
        for (int r = 0; r < HALFV; r++) {
            int c0 = (14 * r) % MODV;
            int c1 = (13 + 14 * r) % MODV;
            v2f v; v.x = Kp[c0] + Kp[c1]; v.y = Kp[c0] - Kp[c1];
            V[r] = v;
        }

        uint hw[HALFV];
        {   // j = 0 (DC, real)
            v2f acc = V[0];
#pragma unroll
            for (int r = 1; r < HALFV; r++) acc += V[r];
            hw[0] = packw(acc);
        }
#pragma unroll
        for (int j = 1; j < 7; j++) {
            v2f re = V[0];
            v2f im; im.x = 0.f; im.y = 0.f;
#pragma unroll
            for (int r = 1; r < HALFV; r++) {
                int a = (j * r) % HALFV;            // compile-time
                re += V[r] * c13[a];
                im -= V[r] * s13[a];
            }
            hw[j]     = packw(re);
            hw[6 + j] = packw(im);
        }
        uint* dst = ws + ((size_t)(((l * MODV + pc) << 6) + i) << 4);
        *(uint4*)(dst)     = make_uint4(hw[0], hw[1], hw[2],  hw[3]);
        *(uint4*)(dst + 4) = make_uint4(hw[4], hw[5], hw[6],  hw[7]);
        *(uint4*)(dst + 8) = make_uint4(hw[8], hw[9], hw[10], hw[11]);
        dst[12] = hw[12];
    }
}

// ---------------------------------------------------------------------------
// Kernel 2: one block (4 waves) per b. Wave w pointwise-multiplies the 16
// spectra for l in [16w,16w+16) in packed fp16, LDS tree combine (packed
// words), wave 0 does the fp32 inverse DFT + unscramble + log epilogue.
// ---------------------------------------------------------------------------
__global__ __launch_bounds__(256, 4)
void chain_kernel(const int* __restrict__ P,
                  const uint* __restrict__ ws,
                  float* __restrict__ out)
{
    __shared__ int Pl[NV];
    __shared__ uint sbuf[2][64][HALFV];  // 6656 B

    int b = blockIdx.x;
    int w = threadIdx.x >> 6;
    int i = threadIdx.x & 63;
    if (threadIdx.x < NV) Pl[threadIdx.x] = P[(b << 6) + threadIdx.x];
    __syncthreads();

    int base = w << 4;

    h2 RE[7], IM[7];                     // IM[0] unused
    {
        const uint* e = ws + ((size_t)(((base * MODV + Pl[base]) << 6) + i) << 4);
        uint4 a = *(const uint4*)e;
        uint4 bq = *(const uint4*)(e + 4);
        uint4 cq = *(const uint4*)(e + 8);
        uint w12 = e[12];
        uint wd[HALFV] = {a.x, a.y, a.z, a.w, bq.x, bq.y, bq.z, bq.w,
                          cq.x, cq.y, cq.z, cq.w, w12};
#pragma unroll
        for (int j = 0; j < 7; j++) RE[j] = bch2(wd[j]);
#pragma unroll
        for (int j = 1; j < 7; j++) IM[j] = bch2(wd[6 + j]);
    }

    uint4 n0, n1, n2; uint n12;
    {
        int l = base + 1;
        const uint* e = ws + ((size_t)(((l * MODV + Pl[l]) << 6) + i) << 4);
        n0 = *(const uint4*)e; n1 = *(const uint4*)(e + 4);
        n2 = *(const uint4*)(e + 8); n12 = e[12];
    }

#pragma unroll 1
    for (int s = 1; s < 16; s++) {
        uint cw[HALFV] = {n0.x, n0.y, n0.z, n0.w, n1.x, n1.y, n1.z, n1.w,
                          n2.x, n2.y, n2.z, n2.w, n12};
        if (s < 15) {
            int l = base + s + 1;
            const uint* e = ws + ((size_t)(((l * MODV + Pl[l]) << 6) + i) << 4);
            n0 = *(const uint4*)e; n1 = *(const uint4*)(e + 4);
            n2 = *(const uint4*)(e + 8); n12 = e[12];
        }
        mulspec_w(RE, IM, cw);
    }

    // tree combine: (w0 <- w1), (w2 <- w3), then w0 <- w2 (packed words)
    if (w == 1 || w == 3) {
        int buf = w >> 1;
#pragma unroll
        for (int j = 0; j < 7; j++) sbuf[buf][i][j] = bcu(RE[j]);
#pragma unroll
        for (int j = 1; j < 7; j++) sbuf[buf][i][6 + j] = bcu(IM[j]);
    }
    __syncthreads();
    if (w == 0) {
        uint K[HALFV];
#pragma unroll
        for (int r = 0; r < HALFV; r++) K[r] = sbuf[0][i][r];
        mulspec_w(RE, IM, K);
    } else if (w == 2) {
        uint K[HALFV];
#pragma unroll
        for (int r = 0; r < HALFV; r++) K[r] = sbuf[1][i][r];
        mulspec_w(RE, IM, K);
#pragma unroll
        for (int j = 0; j < 7; j++) sbuf[1][i][j] = bcu(RE[j]);
#pragma unroll
        for (int j = 1; j < 7; j++) sbuf[1][i][6 + j] = bcu(IM[j]);
    }
    __syncthreads();
    if (w == 0) {
        uint K[HALFV];
#pragma unroll
        for (int r = 0; r < HALFV; r++) K[r] = sbuf[1][i][r];
        mulspec_w(RE, IM, K);

        // fp32 epilogue: inverse DFT (unnormalized; scale cancels), log.
        v2f fRE[7], fIM[7];
#pragma unroll
        for (int j = 0; j < 7; j++) {
            v2f v; v.x = (float)RE[j].x; v.y = (float)RE[j].y; fRE[j] = v;
        }
#pragma unroll
        for (int j = 1; j < 7; j++) {
            v2f v; v.x = (float)IM[j].x; v.y = (float)IM[j].y; fIM[j] = v;
        }

        float c13[HALFV], s13[HALFV];
#pragma unroll
        for (int k = 0; k < HALFV; k++) {
            float a = 0.4833219467f * (float)k;
            __sincosf(a, &s13[k], &c13[k]);
        }
        v2f V[HALFV];
#pragma unroll
        for (int r = 0; r < HALFV; r++) {
            v2f acc = fRE[0];
#pragma unroll
            for (int j = 1; j < 7; j++) {
                int a = (j * r) % HALFV;            // compile-time
                acc += (fRE[j] * c13[a] - fIM[j] * s13[a]) * 2.0f;
            }
            V[r] = acc;
        }

        float tot = 0.f;
#pragma unroll
        for (int r = 0; r < HALFV; r++) tot += V[r].x;
        float invt = 0.5f / tot;

        float u[MODV];
#pragma unroll
        for (int r = 0; r < HALFV; r++) {
            u[(14 * r) % MODV]      = (V[r].x + V[r].y) * invt;
            u[(13 + 14 * r) % MODV] = (V[r].x - V[r].y) * invt;
        }
        float* o = out + ((size_t)(b << 6) + i) * MODV;
#pragma unroll
        for (int c = 0; c < MODV; c++) o[c] = __logf(u[c] + 1e-12f);
    }
}

extern "C" void kernel_launch(void* const* d_in, const int* in_sizes, int n_in,
                              void* d_out, int out_size, void* d_ws, size_t ws_size,
                              hipStream_t stream)
{
    const int*   P  = (const int*)d_in[0];      // (1024, 64) int32
    const float* kp = (const float*)d_in[1];    // (4096, 26) fp32
    float* out = (float*)d_out;                 // log_probs ++ key_probs
    float* key_probs_out = out + (size_t)BV * NV * MODV;
    uint* ws = (uint*)d_ws;                     // 6,815,744 B used

    hipLaunchKernelGGL(prep_kernel, dim3(64, 7), dim3(256), 0, stream,
                       kp, key_probs_out, ws);
    hipLaunchKernelGGL(chain_kernel, dim3(BV), dim3(256), 0, stream,
                       P, ws, out);
}